// Round 2
// baseline (1679.824 us; speedup 1.0000x reference)
//
#include <hip/hip_runtime.h>
#include <math.h>

#define NN 50000
#define EE 800000
#define FIN 128
#define HH 8
#define CC 64
#define HC 512
#define GG 64
#define POOL_SZ (GG * 3 * CC)   // 12288

// ---------------- CSR build ----------------

__global__ void k_init(int* cnt, float* pooled) {
    int i = blockIdx.x * blockDim.x + threadIdx.x;
    if (i < NN) cnt[i] = 0;
    if (i < POOL_SZ) pooled[i] = 0.f;
}

__global__ void k_count(const int* __restrict__ dst, int* cnt) {
    int e = blockIdx.x * blockDim.x + threadIdx.x;
    if (e < EE) atomicAdd(&cnt[dst[e]], 1);
}

#define SCAN_B 256
__global__ void k_scan1(const int* __restrict__ cnt, int* off, int* bsum, int n) {
    __shared__ int s[SCAN_B];
    int i = blockIdx.x * SCAN_B + threadIdx.x;
    int v = (i < n) ? cnt[i] : 0;
    s[threadIdx.x] = v;
    __syncthreads();
    for (int d = 1; d < SCAN_B; d <<= 1) {
        int t = (threadIdx.x >= d) ? s[threadIdx.x - d] : 0;
        __syncthreads();
        s[threadIdx.x] += t;
        __syncthreads();
    }
    if (i < n) off[i] = s[threadIdx.x] - v;           // local exclusive
    if (threadIdx.x == SCAN_B - 1) bsum[blockIdx.x] = s[SCAN_B - 1];
}

__global__ void k_scan2(int* bsum, int nb) {
    __shared__ int s[SCAN_B];
    int v = (threadIdx.x < nb) ? bsum[threadIdx.x] : 0;
    s[threadIdx.x] = v;
    __syncthreads();
    for (int d = 1; d < SCAN_B; d <<= 1) {
        int t = (threadIdx.x >= d) ? s[threadIdx.x - d] : 0;
        __syncthreads();
        s[threadIdx.x] += t;
        __syncthreads();
    }
    if (threadIdx.x < nb) bsum[threadIdx.x] = s[threadIdx.x] - v;  // exclusive
}

__global__ void k_scan3(int* off, const int* __restrict__ bsum, int* cursor, int n, int total) {
    int i = blockIdx.x * blockDim.x + threadIdx.x;
    if (i < n) {
        int v = off[i] + bsum[i / SCAN_B];
        off[i] = v;
        cursor[i] = v;
    }
    if (i == 0) off[n] = total;
}

__global__ void k_fill(const int* __restrict__ src, const int* __restrict__ dst,
                       int* cursor, int* col) {
    int e = blockIdx.x * blockDim.x + threadIdx.x;
    if (e < EE) {
        int p = atomicAdd(&cursor[dst[e]], 1);
        col[p] = src[e];
    }
}

// ---------------- GEMM + fused a_src/a_dst epilogue ----------------
// out h[N,512]; block computes 64 rows x 64 cols (one head). K tiled at 64.

template<int K>
__global__ __launch_bounds__(256) void k_gemm(
        const float* __restrict__ A, const float* __restrict__ W,
        const float* __restrict__ asrc, const float* __restrict__ adst,
        float* __restrict__ hout, float* __restrict__ as_out, float* __restrict__ ad_out,
        int M) {
    __shared__ float As[64][65];
    __shared__ float Ws[64][64];
    const int row0 = blockIdx.x * 64;
    const int head = blockIdx.y;
    const int col0 = head * 64;
    const int tid = threadIdx.x;
    const int tr = tid >> 4, tc = tid & 15;

    float acc[4][4] = {};
    for (int kt = 0; kt < K; kt += 64) {
        for (int idx = tid; idx < 64 * 64; idx += 256) {
            int r = idx >> 6, k = idx & 63;
            int gr = row0 + r;
            As[r][k] = (gr < M) ? A[(size_t)gr * K + kt + k] : 0.f;
        }
        for (int idx = tid; idx < 64 * 64; idx += 256) {
            int k = idx >> 6, c = idx & 63;
            Ws[k][c] = W[(size_t)(kt + k) * HC + col0 + c];
        }
        __syncthreads();

        #pragma unroll 4
        for (int k = 0; k < 64; ++k) {
            float4 w = *(const float4*)&Ws[k][tc * 4];
            float a[4];
            #pragma unroll
            for (int i = 0; i < 4; ++i) a[i] = As[tr * 4 + i][k];
            #pragma unroll
            for (int i = 0; i < 4; ++i) {
                acc[i][0] += a[i] * w.x;
                acc[i][1] += a[i] * w.y;
                acc[i][2] += a[i] * w.z;
                acc[i][3] += a[i] * w.w;
            }
        }
        __syncthreads();
    }

    float4 sa = *(const float4*)&asrc[col0 + tc * 4];
    float4 da = *(const float4*)&adst[col0 + tc * 4];
    #pragma unroll
    for (int i = 0; i < 4; ++i) {
        int gr = row0 + tr * 4 + i;
        bool ok = gr < M;
        if (ok) {
            float4 o;
            o.x = acc[i][0]; o.y = acc[i][1]; o.z = acc[i][2]; o.w = acc[i][3];
            *(float4*)&hout[(size_t)gr * HC + col0 + tc * 4] = o;
        }
        float ps = acc[i][0] * sa.x + acc[i][1] * sa.y + acc[i][2] * sa.z + acc[i][3] * sa.w;
        float pd = acc[i][0] * da.x + acc[i][1] * da.y + acc[i][2] * da.z + acc[i][3] * da.w;
        ps += __shfl_xor(ps, 1); ps += __shfl_xor(ps, 2);
        ps += __shfl_xor(ps, 4); ps += __shfl_xor(ps, 8);
        pd += __shfl_xor(pd, 1); pd += __shfl_xor(pd, 2);
        pd += __shfl_xor(pd, 4); pd += __shfl_xor(pd, 8);
        if (ok && tc == 0) {
            as_out[gr * HH + head] = ps;
            ad_out[gr * HH + head] = pd;
        }
    }
}

// ---------------- Per-destination-node aggregation ----------------
// block = 512 threads, one block per dst node.
// Phase 1 (wave 0): softmax max+denom per head over incoming edges (+self).
// Phase 2: chunk per-edge alpha into LDS, all threads accumulate sum alpha*h[src].
// Epilogue: head mean + bias + ELU, write y, atomicAdd pooled.

__global__ __launch_bounds__(512) void k_agg(
        const float* __restrict__ hbuf, const float* __restrict__ as,
        const float* __restrict__ ad, const int* __restrict__ off,
        const int* __restrict__ col, const float* __restrict__ bias,
        const int* __restrict__ batch, float* __restrict__ yout,
        float* __restrict__ pooled, int layerOff) {
    __shared__ float s_ad[HH], s_m[HH], s_d[HH];
    __shared__ float s_alpha[64 * HH];
    __shared__ int s_col[64];
    __shared__ float s_red[512];

    const int n = blockIdx.x;
    const int t = threadIdx.x;
    if (t < HH) s_ad[t] = ad[n * HH + t];
    const int e0 = off[n];
    const int deg = off[n + 1] - e0;
    const int tot = deg + 1;            // + self loop
    __syncthreads();

    if (t < 64) {
        int h = t & 7, sub = t >> 3;
        float adh = s_ad[h];
        float m = -1e30f;
        for (int j = sub; j < tot; j += 8) {
            int s = (j < deg) ? col[e0 + j] : n;
            float e = as[s * HH + h] + adh;
            e = e > 0.f ? e : 0.2f * e;
            m = fmaxf(m, e);
        }
        m = fmaxf(m, __shfl_xor(m, 8));
        m = fmaxf(m, __shfl_xor(m, 16));
        m = fmaxf(m, __shfl_xor(m, 32));
        float sum = 0.f;
        for (int j = sub; j < tot; j += 8) {
            int s = (j < deg) ? col[e0 + j] : n;
            float e = as[s * HH + h] + adh;
            e = e > 0.f ? e : 0.2f * e;
            sum += __expf(e - m);
        }
        sum += __shfl_xor(sum, 8);
        sum += __shfl_xor(sum, 16);
        sum += __shfl_xor(sum, 32);
        if (t < HH) { s_m[t] = m; s_d[t] = sum; }
    }
    __syncthreads();

    const int h = t >> 6;      // 0..7
    const int c = t & 63;      // 0..63
    float acc = 0.f;
    for (int base = 0; base < tot; base += 64) {
        int cnt = min(64, tot - base);
        __syncthreads();                         // protect s_alpha/s_col reuse
        int jj = t >> 3, hh = t & 7;
        if (jj < cnt) {
            int j = base + jj;
            int s = (j < deg) ? col[e0 + j] : n;
            if (hh == 0) s_col[jj] = s;
            float e = as[s * HH + hh] + s_ad[hh];
            e = e > 0.f ? e : 0.2f * e;
            s_alpha[jj * HH + hh] = __expf(e - s_m[hh]) / s_d[hh];
        }
        __syncthreads();
        for (int j2 = 0; j2 < cnt; ++j2) {
            int s = s_col[j2];
            acc += s_alpha[j2 * HH + h] * hbuf[(size_t)s * HC + h * CC + c];
        }
    }

    s_red[t] = acc;
    __syncthreads();
    if (t < CC) {
        float v = 0.f;
        #pragma unroll
        for (int hh2 = 0; hh2 < HH; ++hh2) v += s_red[hh2 * CC + t];
        v = v * 0.125f + bias[t];
        v = v > 0.f ? v : (__expf(v) - 1.f);     // ELU
        yout[(size_t)n * CC + t] = v;
        atomicAdd(&pooled[batch[n] * (3 * CC) + layerOff + t], v);
    }
}

// ---------------- launch ----------------

extern "C" void kernel_launch(void* const* d_in, const int* in_sizes, int n_in,
                              void* d_out, int out_size, void* d_ws, size_t ws_size,
                              hipStream_t stream) {
    const float* x      = (const float*)d_in[0];
    const int*   ei     = (const int*)d_in[1];
    const int*   batch  = (const int*)d_in[2];
    const float* W0     = (const float*)d_in[4];
    const float* asrc0  = (const float*)d_in[5];
    const float* adst0  = (const float*)d_in[6];
    const float* b0     = (const float*)d_in[7];
    const float* W1     = (const float*)d_in[8];
    const float* asrc1  = (const float*)d_in[9];
    const float* adst1  = (const float*)d_in[10];
    const float* b1     = (const float*)d_in[11];
    const float* W2     = (const float*)d_in[12];
    const float* asrc2  = (const float*)d_in[13];
    const float* adst2  = (const float*)d_in[14];
    const float* b2     = (const float*)d_in[15];

    const int* src = ei;
    const int* dst = ei + EE;

    float* outp   = (float*)d_out;
    float* pooled = outp;                 // [64,192]
    float* hfinal = outp + POOL_SZ;       // [N,64]

    // workspace layout
    float* h      = (float*)d_ws;              // N*512
    float* y      = h + (size_t)NN * HC;       // N*64
    float* as_buf = y + (size_t)NN * CC;       // N*8
    float* ad_buf = as_buf + (size_t)NN * HH;  // N*8
    int*   off    = (int*)(ad_buf + (size_t)NN * HH);  // N+1
    int*   cursor = off + (NN + 1);            // N
    int*   cnt    = cursor + NN;               // N
    int*   col    = cnt + NN;                  // E
    int*   bsum   = col + EE;                  // <=256

    const int NB = (NN + SCAN_B - 1) / SCAN_B;   // 196

    k_init<<<(NN + 255) / 256, 256, 0, stream>>>(cnt, pooled);
    k_count<<<(EE + 255) / 256, 256, 0, stream>>>(dst, cnt);
    k_scan1<<<NB, SCAN_B, 0, stream>>>(cnt, off, bsum, NN);
    k_scan2<<<1, SCAN_B, 0, stream>>>(bsum, NB);
    k_scan3<<<(NN + 255) / 256, 256, 0, stream>>>(off, bsum, cursor, NN, EE);
    k_fill<<<(EE + 255) / 256, 256, 0, stream>>>(src, dst, cursor, col);

    dim3 ggrid((NN + 63) / 64, HH);

    // layer 0
    k_gemm<FIN><<<ggrid, 256, 0, stream>>>(x, W0, asrc0, adst0, h, as_buf, ad_buf, NN);
    k_agg<<<NN, 512, 0, stream>>>(h, as_buf, ad_buf, off, col, b0, batch, y, pooled, 0);
    // layer 1
    k_gemm<CC><<<ggrid, 256, 0, stream>>>(y, W1, asrc1, adst1, h, as_buf, ad_buf, NN);
    k_agg<<<NN, 512, 0, stream>>>(h, as_buf, ad_buf, off, col, b1, batch, y, pooled, CC);
    // layer 2
    k_gemm<CC><<<ggrid, 256, 0, stream>>>(y, W2, asrc2, adst2, h, as_buf, ad_buf, NN);
    k_agg<<<NN, 512, 0, stream>>>(h, as_buf, ad_buf, off, col, b2, batch, hfinal, pooled, 2 * CC);
}

// Round 3
// 1555.945 us; speedup vs baseline: 1.0796x; 1.0796x over previous
//
#include <hip/hip_runtime.h>
#include <math.h>

#define NN 50000
#define EE 800000
#define FIN 128
#define HH 8
#define CC 64
#define HC 512
#define GG 64
#define POOL_SZ (GG * 3 * CC)   // 12288
#define CH 128                  // edge chunk per softmax/gather pass

// ---------------- CSR build ----------------

__global__ void k_init(int* cnt, float* pooled) {
    int i = blockIdx.x * blockDim.x + threadIdx.x;
    if (i < NN) cnt[i] = 0;
    if (i < POOL_SZ) pooled[i] = 0.f;
}

__global__ void k_count(const int* __restrict__ dst, int* cnt) {
    int e = blockIdx.x * blockDim.x + threadIdx.x;
    if (e < EE) atomicAdd(&cnt[dst[e]], 1);
}

#define SCAN_B 256
__global__ void k_scan1(const int* __restrict__ cnt, int* off, int* bsum, int n) {
    __shared__ int s[SCAN_B];
    int i = blockIdx.x * SCAN_B + threadIdx.x;
    int v = (i < n) ? cnt[i] : 0;
    s[threadIdx.x] = v;
    __syncthreads();
    for (int d = 1; d < SCAN_B; d <<= 1) {
        int t = (threadIdx.x >= d) ? s[threadIdx.x - d] : 0;
        __syncthreads();
        s[threadIdx.x] += t;
        __syncthreads();
    }
    if (i < n) off[i] = s[threadIdx.x] - v;           // local exclusive
    if (threadIdx.x == SCAN_B - 1) bsum[blockIdx.x] = s[SCAN_B - 1];
}

__global__ void k_scan2(int* bsum, int nb) {
    __shared__ int s[SCAN_B];
    int v = (threadIdx.x < nb) ? bsum[threadIdx.x] : 0;
    s[threadIdx.x] = v;
    __syncthreads();
    for (int d = 1; d < SCAN_B; d <<= 1) {
        int t = (threadIdx.x >= d) ? s[threadIdx.x - d] : 0;
        __syncthreads();
        s[threadIdx.x] += t;
        __syncthreads();
    }
    if (threadIdx.x < nb) bsum[threadIdx.x] = s[threadIdx.x] - v;  // exclusive
}

__global__ void k_scan3(int* off, const int* __restrict__ bsum, int* cursor, int n, int total) {
    int i = blockIdx.x * blockDim.x + threadIdx.x;
    if (i < n) {
        int v = off[i] + bsum[i / SCAN_B];
        off[i] = v;
        cursor[i] = v;
    }
    if (i == 0) off[n] = total;
}

__global__ void k_fill(const int* __restrict__ src, const int* __restrict__ dst,
                       int* cursor, int* col) {
    int e = blockIdx.x * blockDim.x + threadIdx.x;
    if (e < EE) {
        int p = atomicAdd(&cursor[dst[e]], 1);
        col[p] = src[e];
    }
}

// ---------------- GEMM + fused a_src/a_dst epilogue ----------------
// out h[N,512]; block computes 64 rows x 64 cols (one head). K tiled at 64.

template<int K>
__global__ __launch_bounds__(256) void k_gemm(
        const float* __restrict__ A, const float* __restrict__ W,
        const float* __restrict__ asrc, const float* __restrict__ adst,
        float* __restrict__ hout, float* __restrict__ as_out, float* __restrict__ ad_out,
        int M) {
    __shared__ float As[64][65];
    __shared__ float Ws[64][64];
    const int row0 = blockIdx.x * 64;
    const int head = blockIdx.y;
    const int col0 = head * 64;
    const int tid = threadIdx.x;
    const int tr = tid >> 4, tc = tid & 15;

    float acc[4][4] = {};
    for (int kt = 0; kt < K; kt += 64) {
        for (int idx = tid; idx < 64 * 64; idx += 256) {
            int r = idx >> 6, k = idx & 63;
            int gr = row0 + r;
            As[r][k] = (gr < M) ? A[(size_t)gr * K + kt + k] : 0.f;
        }
        for (int idx = tid; idx < 64 * 64; idx += 256) {
            int k = idx >> 6, c = idx & 63;
            Ws[k][c] = W[(size_t)(kt + k) * HC + col0 + c];
        }
        __syncthreads();

        #pragma unroll 4
        for (int k = 0; k < 64; ++k) {
            float4 w = *(const float4*)&Ws[k][tc * 4];
            float a[4];
            #pragma unroll
            for (int i = 0; i < 4; ++i) a[i] = As[tr * 4 + i][k];
            #pragma unroll
            for (int i = 0; i < 4; ++i) {
                acc[i][0] += a[i] * w.x;
                acc[i][1] += a[i] * w.y;
                acc[i][2] += a[i] * w.z;
                acc[i][3] += a[i] * w.w;
            }
        }
        __syncthreads();
    }

    float4 sa = *(const float4*)&asrc[col0 + tc * 4];
    float4 da = *(const float4*)&adst[col0 + tc * 4];
    #pragma unroll
    for (int i = 0; i < 4; ++i) {
        int gr = row0 + tr * 4 + i;
        bool ok = gr < M;
        if (ok) {
            float4 o;
            o.x = acc[i][0]; o.y = acc[i][1]; o.z = acc[i][2]; o.w = acc[i][3];
            *(float4*)&hout[(size_t)gr * HC + col0 + tc * 4] = o;
        }
        float ps = acc[i][0] * sa.x + acc[i][1] * sa.y + acc[i][2] * sa.z + acc[i][3] * sa.w;
        float pd = acc[i][0] * da.x + acc[i][1] * da.y + acc[i][2] * da.z + acc[i][3] * da.w;
        ps += __shfl_xor(ps, 1); ps += __shfl_xor(ps, 2);
        ps += __shfl_xor(ps, 4); ps += __shfl_xor(ps, 8);
        pd += __shfl_xor(pd, 1); pd += __shfl_xor(pd, 2);
        pd += __shfl_xor(pd, 4); pd += __shfl_xor(pd, 8);
        if (ok && tc == 0) {
            as_out[gr * HH + head] = ps;
            ad_out[gr * HH + head] = pd;
        }
    }
}

// ---------------- Per-destination-node aggregation (flash-style) ----------------
// 256 threads per node. Thread t owns float2 (channels 2t,2t+1) of the 512-wide
// row; head h = t>>5. Softmax e-values computed once into LDS with coalesced
// reads, online-rescaled across CH-edge chunks; gather unrolled x4 for MLP.

__global__ __launch_bounds__(256) void k_agg(
        const float* __restrict__ hbuf, const float* __restrict__ as,
        const float* __restrict__ ad, const int* __restrict__ off,
        const int* __restrict__ col, const float* __restrict__ bias,
        const int* __restrict__ batch, float* __restrict__ yout,
        float* __restrict__ pooled, int layerOff) {
    __shared__ float s_ad[HH], s_m[HH], s_d[HH], s_scale[HH];
    __shared__ float s_e[CH][HH];      // e, then softmax numerator
    __shared__ int   s_col[CH];
    __shared__ float2 s_red[256];

    const int n = blockIdx.x;
    const int t = threadIdx.x;
    const int e0 = off[n];
    const int deg = off[n + 1] - e0;
    const int tot = deg + 1;           // + self loop
    if (t < HH) { s_ad[t] = ad[n * HH + t]; s_m[t] = -1e30f; s_d[t] = 0.f; }

    const int h  = t >> 5;             // head for gather/epilogue
    const int hl = t & 7;              // head for e-compute
    const int jl = t >> 3;             // j-slot 0..31 for e-compute
    const int tt2 = t * 2;             // element offset within 512-row
    float2 acc = make_float2(0.f, 0.f);

    for (int base = 0; base < tot; base += CH) {
        const int cnt = min(CH, tot - base);
        __syncthreads();               // protect s_e/s_col from prev-iter readers
        if (t < cnt) {
            int gj = base + t;
            s_col[t] = (gj < deg) ? col[e0 + gj] : n;   // j==deg -> self loop
        }
        __syncthreads();
        // e(j,h): 8 consecutive threads read one 32B as-row => coalesced
        for (int j = jl; j < cnt; j += 32) {
            int s = s_col[j];
            float e = as[s * HH + hl] + s_ad[hl];
            s_e[j][hl] = e > 0.f ? e : 0.2f * e;
        }
        __syncthreads();
        // wave 0: chunk max -> online combine -> numerators + denom
        if (t < 64) {
            int hh = t & 7, sub = t >> 3;
            float mc = -1e30f;
            for (int j = sub; j < cnt; j += 8) mc = fmaxf(mc, s_e[j][hh]);
            mc = fmaxf(mc, __shfl_xor(mc, 8));
            mc = fmaxf(mc, __shfl_xor(mc, 16));
            mc = fmaxf(mc, __shfl_xor(mc, 32));
            float mold = s_m[hh];
            float mnew = fmaxf(mold, mc);
            float sc = __expf(mold - mnew);            // first chunk: exp(-inf)=0
            float sum = 0.f;
            for (int j = sub; j < cnt; j += 8) {
                float num = __expf(s_e[j][hh] - mnew);
                s_e[j][hh] = num;
                sum += num;
            }
            sum += __shfl_xor(sum, 8);
            sum += __shfl_xor(sum, 16);
            sum += __shfl_xor(sum, 32);
            if (sub == 0) {
                s_m[hh] = mnew;
                s_scale[hh] = sc;
                s_d[hh] = s_d[hh] * sc + sum;
            }
        }
        __syncthreads();
        // gather, x4 unrolled: 4 independent float2 loads in flight
        float rs = s_scale[h];
        acc.x *= rs; acc.y *= rs;
        int j = 0;
        for (; j + 4 <= cnt; j += 4) {
            int s0 = s_col[j], s1 = s_col[j + 1], s2 = s_col[j + 2], s3 = s_col[j + 3];
            float2 v0 = *(const float2*)&hbuf[(size_t)s0 * HC + tt2];
            float2 v1 = *(const float2*)&hbuf[(size_t)s1 * HC + tt2];
            float2 v2 = *(const float2*)&hbuf[(size_t)s2 * HC + tt2];
            float2 v3 = *(const float2*)&hbuf[(size_t)s3 * HC + tt2];
            float a0 = s_e[j][h], a1 = s_e[j + 1][h];
            float a2 = s_e[j + 2][h], a3 = s_e[j + 3][h];
            acc.x += a0 * v0.x + a1 * v1.x + a2 * v2.x + a3 * v3.x;
            acc.y += a0 * v0.y + a1 * v1.y + a2 * v2.y + a3 * v3.y;
        }
        for (; j < cnt; ++j) {
            int s = s_col[j];
            float2 v = *(const float2*)&hbuf[(size_t)s * HC + tt2];
            float a = s_e[j][h];
            acc.x += a * v.x;
            acc.y += a * v.y;
        }
    }

    float dinv = 1.f / s_d[h];
    acc.x *= dinv; acc.y *= dinv;
    s_red[t] = acc;
    __syncthreads();
    // head mean + bias + ELU + write + pool  (32 threads, float2 each)
    if (t < 32) {
        float2 v = make_float2(0.f, 0.f);
        #pragma unroll
        for (int hh = 0; hh < HH; ++hh) {
            float2 r = s_red[hh * 32 + t];
            v.x += r.x; v.y += r.y;
        }
        v.x = v.x * 0.125f + bias[t * 2];
        v.y = v.y * 0.125f + bias[t * 2 + 1];
        v.x = v.x > 0.f ? v.x : (__expf(v.x) - 1.f);
        v.y = v.y > 0.f ? v.y : (__expf(v.y) - 1.f);
        *(float2*)&yout[(size_t)n * CC + t * 2] = v;
        int g = batch[n];
        atomicAdd(&pooled[g * (3 * CC) + layerOff + t * 2], v.x);
        atomicAdd(&pooled[g * (3 * CC) + layerOff + t * 2 + 1], v.y);
    }
}

// ---------------- launch ----------------

extern "C" void kernel_launch(void* const* d_in, const int* in_sizes, int n_in,
                              void* d_out, int out_size, void* d_ws, size_t ws_size,
                              hipStream_t stream) {
    const float* x      = (const float*)d_in[0];
    const int*   ei     = (const int*)d_in[1];
    const int*   batch  = (const int*)d_in[2];
    const float* W0     = (const float*)d_in[4];
    const float* asrc0  = (const float*)d_in[5];
    const float* adst0  = (const float*)d_in[6];
    const float* b0     = (const float*)d_in[7];
    const float* W1     = (const float*)d_in[8];
    const float* asrc1  = (const float*)d_in[9];
    const float* adst1  = (const float*)d_in[10];
    const float* b1     = (const float*)d_in[11];
    const float* W2     = (const float*)d_in[12];
    const float* asrc2  = (const float*)d_in[13];
    const float* adst2  = (const float*)d_in[14];
    const float* b2     = (const float*)d_in[15];

    const int* src = ei;
    const int* dst = ei + EE;

    float* outp   = (float*)d_out;
    float* pooled = outp;                 // [64,192]
    float* hfinal = outp + POOL_SZ;       // [N,64]

    // workspace layout
    float* h      = (float*)d_ws;              // N*512
    float* y      = h + (size_t)NN * HC;       // N*64
    float* as_buf = y + (size_t)NN * CC;       // N*8
    float* ad_buf = as_buf + (size_t)NN * HH;  // N*8
    int*   off    = (int*)(ad_buf + (size_t)NN * HH);  // N+1
    int*   cursor = off + (NN + 1);            // N
    int*   cnt    = cursor + NN;               // N
    int*   col    = cnt + NN;                  // E
    int*   bsum   = col + EE;                  // <=256

    const int NB = (NN + SCAN_B - 1) / SCAN_B;   // 196

    k_init<<<(NN + 255) / 256, 256, 0, stream>>>(cnt, pooled);
    k_count<<<(EE + 255) / 256, 256, 0, stream>>>(dst, cnt);
    k_scan1<<<NB, SCAN_B, 0, stream>>>(cnt, off, bsum, NN);
    k_scan2<<<1, SCAN_B, 0, stream>>>(bsum, NB);
    k_scan3<<<(NN + 255) / 256, 256, 0, stream>>>(off, bsum, cursor, NN, EE);
    k_fill<<<(EE + 255) / 256, 256, 0, stream>>>(src, dst, cursor, col);

    dim3 ggrid((NN + 63) / 64, HH);

    // layer 0
    k_gemm<FIN><<<ggrid, 256, 0, stream>>>(x, W0, asrc0, adst0, h, as_buf, ad_buf, NN);
    k_agg<<<NN, 256, 0, stream>>>(h, as_buf, ad_buf, off, col, b0, batch, y, pooled, 0);
    // layer 1
    k_gemm<CC><<<ggrid, 256, 0, stream>>>(y, W1, asrc1, adst1, h, as_buf, ad_buf, NN);
    k_agg<<<NN, 256, 0, stream>>>(h, as_buf, ad_buf, off, col, b1, batch, y, pooled, CC);
    // layer 2
    k_gemm<CC><<<ggrid, 256, 0, stream>>>(y, W2, asrc2, adst2, h, as_buf, ad_buf, NN);
    k_agg<<<NN, 256, 0, stream>>>(h, as_buf, ad_buf, off, col, b2, batch, hfinal, pooled, 2 * CC);
}